// Round 5
// baseline (64.255 us; speedup 1.0000x reference)
//
#include <hip/hip_runtime.h>
#include <math.h>

// EdgeAwareLoss — round 8: full-width bands, doubled grid for occupancy.
//
// r7 post-mortem (counters): FETCH=73.5MB (target L3-absorbed), HBM 1.1TB/s,
// VALU 21%, Occupancy 36% — latency-bound at 512 blocks = 2 blocks/CU with a
// 6-barrier serial pipeline. r8: RB 32->16, NT 512->256, grid 512->1024
// (4 blocks/CU co-resident; LDS 48->27KB allows 5). Cross-block overlap hides
// stage latency: blocks at stage D stream pred while others run SWAR stages.
//
// Exactness vs JAX reference (bit-sliced pipeline validated absmax 0.0
// r5-r7; identical integer math, band geometry parameterized by RB):
//  - img=(t>0.5)*255 => m multiple of 255 => weak==strong => strong==cand.
//  - gx,gy in [-4,4] (255-units), m=|gx|+|gy|<=6: 3 bit-planes.
//  - horiz: ay==0&&ax>=1 || ay==1&&ax>=3 ; vert: ax==0&&ay>=1 || ax==1&&ay>=3
//  - Row bit j of word w = col 64w+j; cross-word shifts carry from neighbor
//    words; image borders edge-replicate for Sobel; cand masked to interior.
//  - Horizontal dilate: 0 outside image (reduce_window 0-pad). Vertical
//    dilate: halo cand rows computed, rows outside [1,1022] masked 0.
//  - bce = -max(log(t?p:1-p),-100); 1-p exact for p>=0.5 (Sterbenz).

typedef unsigned long long u64;
typedef unsigned int u32;
typedef unsigned char u8;

#define NT 256
#define RB 16                  // rows per band
#define H_IMG 1024
#define W_IMG 1024
#define NBANDS (H_IMG / RB)    // 64

__device__ __forceinline__ u64 gt3(u64 a2, u64 a1, u64 a0,
                                   u64 b2, u64 b1, u64 b0)
{
    u64 e2 = ~(a2 ^ b2), g2 = a2 & ~b2;
    u64 e1 = ~(a1 ^ b1), g1 = a1 & ~b1;
    u64 g0 = a0 & ~b0;
    return g2 | (e2 & (g1 | (e1 & g0)));
}

__global__ __launch_bounds__(NT, 4)
void edge_loss_kernel(const float* __restrict__ pred,
                      const float* __restrict__ target,
                      float* __restrict__ partials,
                      u32* __restrict__ done_ctr,
                      float* __restrict__ out,
                      int nblocks, double invN)
{
    __shared__ u64 bl[(RB + 8) * 16];         // target bits; bl row i = img row r0-4+i
    __shared__ u64 m0[(RB + 6) * 16], m1[(RB + 6) * 16], m2[(RB + 6) * 16];
    __shared__ u64 hz[(RB + 6) * 16], vt[(RB + 6) * 16], sdp[(RB + 6) * 16];
    __shared__ u64 cnd[(RB + 4) * 16];        // cand; ci = img row r0-2+ci
    __shared__ u64 hrr[(RB + 4) * 16];        // horiz 5-OR of cand
    __shared__ u64 ezz[RB * 16];              // edge-zone bits for band rows
    __shared__ float wsum[NT / 64];
    __shared__ double dsum[NT / 64];
    __shared__ u32 lastf;

    const int tid = threadIdx.x;
    const int band = blockIdx.x;
    const int bz = blockIdx.y;
    const int r0 = band * RB;
    const float* pimg = pred + (size_t)bz * H_IMG * W_IMG;
    const float* timg = target + (size_t)bz * H_IMG * W_IMG;

    // ---- Stage 0: binarize target slab (contiguous rows) into bit rows ----
    {
        u8* bl8 = (u8*)bl;
        const float4* tp4 = (const float4*)timg;
#pragma unroll
        for (int j = 0; j < (RB + 8) * 128 / NT; ++j) {   // 24 rows * 128 B
            int bidx = tid + NT * j;
            int row = bidx >> 7;
            int bc = bidx & 127;
            int tr = r0 - 4 + row; tr = tr < 0 ? 0 : (tr > H_IMG - 1 ? H_IMG - 1 : tr);
            int fi = tr * (W_IMG / 4) + bc * 2;
            float4 f0 = tp4[fi], f1 = tp4[fi + 1];
            u32 b = (f0.x > 0.5f ? 1u : 0u)  | (f0.y > 0.5f ? 2u : 0u)
                  | (f0.z > 0.5f ? 4u : 0u)  | (f0.w > 0.5f ? 8u : 0u)
                  | (f1.x > 0.5f ? 16u : 0u) | (f1.y > 0.5f ? 32u : 0u)
                  | (f1.z > 0.5f ? 64u : 0u) | (f1.w > 0.5f ? 128u : 0u);
            bl8[bidx] = (u8)b;
        }
    }
    __syncthreads();

    // ---- Stage A: bit-sliced Sobel -> m planes + class planes ----
    for (int t = tid; t < (RB + 6) * 16; t += NT) {
        int mi = t >> 4, w = t & 15;
        const u64* ra = &bl[mi * 16];
        const u64* rb = ra + 16;
        const u64* rc = rb + 16;
        u64 A = ra[w], Bq = rb[w], C = rc[w];
        u64 Acl = w ? (ra[w - 1] >> 63) : (A & 1ULL);
        u64 Bcl = w ? (rb[w - 1] >> 63) : (Bq & 1ULL);
        u64 Ccl = w ? (rc[w - 1] >> 63) : (C & 1ULL);
        u64 Acr = (w < 15) ? (ra[w + 1] << 63) : (A & 0x8000000000000000ULL);
        u64 Bcr = (w < 15) ? (rb[w + 1] << 63) : (Bq & 0x8000000000000000ULL);
        u64 Ccr = (w < 15) ? (rc[w + 1] << 63) : (C & 0x8000000000000000ULL);
        u64 AL = (A << 1) | Acl, AR = (A >> 1) | Acr;
        u64 BL = (Bq << 1) | Bcl, BR = (Bq >> 1) | Bcr;
        u64 CL = (C << 1) | Ccl, CR = (C >> 1) | Ccr;

        u64 sx = AR ^ CR, cxk = AR & CR;
        u64 Px1 = BR ^ cxk, Px2 = BR & cxk;
        u64 sn = AL ^ CL, cnk = AL & CL;
        u64 Nx1 = BL ^ cnk, Nx2 = BL & cnk;
        u64 d0 = sx ^ sn;
        u64 ca = sx | ~sn;
        u64 nb1 = ~Nx1, t1 = Px1 ^ nb1, d1 = t1 ^ ca;
        u64 cb = (Px1 & nb1) | (ca & t1);
        u64 nb2 = ~Nx2, t2 = Px2 ^ nb2, d2 = t2 ^ cb;
        u64 cc = (Px2 & nb2) | (cb & t2);
        u64 sgx = ~cc;                         // gx < 0
        u64 ax0 = d0;
        u64 ax1 = d1 ^ (sgx & d0);
        u64 ax2 = d2 ^ (sgx & (d0 | d1));

        u64 sy = CL ^ CR, cyk = CL & CR;
        u64 Py1 = C ^ cyk, Py2 = C & cyk;
        u64 sm = AL ^ AR, cmk = AL & AR;
        u64 Ny1 = A ^ cmk, Ny2 = A & cmk;
        u64 e0 = sy ^ sm;
        u64 ka = sy | ~sm;
        u64 mb1 = ~Ny1, u1 = Py1 ^ mb1, f1 = u1 ^ ka;
        u64 kb = (Py1 & mb1) | (ka & u1);
        u64 mb2 = ~Ny2, u2 = Py2 ^ mb2, f2 = u2 ^ kb;
        u64 kc = (Py2 & mb2) | (kb & u2);
        u64 sgy = ~kc;                         // gy < 0
        u64 ay0 = e0;
        u64 ay1 = f1 ^ (sgy & e0);
        u64 ay2 = f2 ^ (sgy & (e0 | f1));

        u64 s0 = ax0 ^ ay0, q0 = ax0 & ay0;
        u64 tt = ax1 ^ ay1, s1 = tt ^ q0;
        u64 q1 = (ax1 & ay1) | (q0 & tt);
        u64 s2 = ax2 ^ ay2 ^ q1;
        m0[t] = s0; m1[t] = s1; m2[t] = s2;

        u64 ax12 = ax1 | ax2, axnz = ax0 | ax12;
        u64 axe1 = ax0 & ~ax12, axg3 = ax2 | (ax1 & ax0);
        u64 ay12 = ay1 | ay2, aynz = ay0 | ay12;
        u64 aye1 = ay0 & ~ay12, ayg3 = ay2 | (ay1 & ay0);
        hz[t] = (axnz & ~aynz) | (aye1 & axg3);
        vt[t] = (aynz & ~axnz) | (axe1 & ayg3);
        u64 gxp = axnz & ~sgx, gyp = aynz & ~sgy;
        sdp[t] = (gxp & sgy) | (sgx & gyp);
    }
    __syncthreads();

    // ---- Stage B: bit-sliced NMS + threshold + interior -> cand ----
    for (int t = tid; t < (RB + 4) * 16; t += NT) {
        int ci = t >> 4, w = t & 15;
        int iu = ci * 16 + w, im = iu + 16, id = iu + 32;
        u64 M0c = m0[im], M1c = m1[im], M2c = m2[im];
        u64 U0c = m0[iu], U1c = m1[iu], U2c = m2[iu];
        u64 D0c = m0[id], D1c = m1[id], D2c = m2[id];
        u64 M0l = 0, M1l = 0, M2l = 0, U0l = 0, U1l = 0, U2l = 0,
            D0l = 0, D1l = 0, D2l = 0;
        if (w) {
            M0l = m0[im - 1]; M1l = m1[im - 1]; M2l = m2[im - 1];
            U0l = m0[iu - 1]; U1l = m1[iu - 1]; U2l = m2[iu - 1];
            D0l = m0[id - 1]; D1l = m1[id - 1]; D2l = m2[id - 1];
        }
        u64 M0r = 0, M1r = 0, M2r = 0, U0r = 0, U1r = 0, U2r = 0,
            D0r = 0, D1r = 0, D2r = 0;
        if (w < 15) {
            M0r = m0[im + 1]; M1r = m1[im + 1]; M2r = m2[im + 1];
            U0r = m0[iu + 1]; U1r = m1[iu + 1]; U2r = m2[iu + 1];
            D0r = m0[id + 1]; D1r = m1[id + 1]; D2r = m2[id + 1];
        }
        u64 ML0 = (M0c << 1) | (M0l >> 63), ML1 = (M1c << 1) | (M1l >> 63),
            ML2 = (M2c << 1) | (M2l >> 63);
        u64 MR0 = (M0c >> 1) | (M0r << 63), MR1 = (M1c >> 1) | (M1r << 63),
            MR2 = (M2c >> 1) | (M2r << 63);
        u64 UL0 = (U0c << 1) | (U0l >> 63), UL1 = (U1c << 1) | (U1l >> 63),
            UL2 = (U2c << 1) | (U2l >> 63);
        u64 UR0 = (U0c >> 1) | (U0r << 63), UR1 = (U1c >> 1) | (U1r << 63),
            UR2 = (U2c >> 1) | (U2r << 63);
        u64 DL0 = (D0c << 1) | (D0l >> 63), DL1 = (D1c << 1) | (D1l >> 63),
            DL2 = (D2c << 1) | (D2l >> 63);
        u64 DR0 = (D0c >> 1) | (D0r << 63), DR1 = (D1c >> 1) | (D1r << 63),
            DR2 = (D2c >> 1) | (D2r << 63);

        u64 kH = gt3(M2c, M1c, M0c, ML2, ML1, ML0) &
                ~gt3(MR2, MR1, MR0, M2c, M1c, M0c);
        u64 kV = gt3(M2c, M1c, M0c, U2c, U1c, U0c) &
                ~gt3(D2c, D1c, D0c, M2c, M1c, M0c);
        u64 kA = gt3(M2c, M1c, M0c, UR2, UR1, UR0) &
                ~gt3(DL2, DL1, DL0, M2c, M1c, M0c);
        u64 kB = gt3(M2c, M1c, M0c, UL2, UL1, UL0) &
                ~gt3(DR2, DR1, DR0, M2c, M1c, M0c);

        u64 H = hz[im], V = vt[im], S = sdp[im];
        u64 nHV = ~(H | V);
        u64 keep = (H & kH) | (V & kV) | (nHV & ((S & kA) | (~S & kB)));
        u64 cand = keep & (M0c | M1c | M2c);
        if (w == 0)  cand &= ~1ULL;
        if (w == 15) cand &= ~0x8000000000000000ULL;
        int rr = r0 - 2 + ci;
        if (rr < 1 || rr > H_IMG - 2) cand = 0;
        cnd[t] = cand;
    }
    __syncthreads();

    // ---- Stage C: horizontal 5-OR (0 outside image == 0-pad dilate) ----
    for (int t = tid; t < (RB + 4) * 16; t += NT) {
        int w = t & 15;
        u64 c = cnd[t];
        u64 cl = w ? cnd[t - 1] : 0;
        u64 cr = (w < 15) ? cnd[t + 1] : 0;
        hrr[t] = c | (c << 1) | (cl >> 63) | (c << 2) | (cl >> 62)
                   | (c >> 1) | (cr << 63) | (c >> 2) | (cr << 62);
    }
    __syncthreads();

    // ---- Stage C2: vertical 5-OR -> edge-zone bits for band rows ----
    for (int t = tid; t < RB * 16; t += NT)
        ezz[t] = hrr[t] | hrr[t + 16] | hrr[t + 32] | hrr[t + 48] | hrr[t + 64];
    __syncthreads();

    // ---- Stage D: weighted BCE over the contiguous pred slab ----
    float acc = 0.0f;
    {
        const float4* pp4 = (const float4*)(pimg + (size_t)r0 * W_IMG);
#pragma unroll 4
        for (int k = 0; k < RB * 256 / NT; ++k) {   // 16 rows * 256 float4
            int fi = tid + NT * k;
            float4 pv = pp4[fi];
            int px = fi << 2;
            int row = px >> 10;
            int w = (px >> 6) & 15;
            int sh = px & 63;
            u32 tb = (u32)(bl[(row + 4) * 16 + w] >> sh);
            u32 eb = (u32)(ezz[row * 16 + w] >> sh);
            float ps[4] = {pv.x, pv.y, pv.z, pv.w};
#pragma unroll
            for (int c2 = 0; c2 < 4; ++c2) {
                float p = ps[c2];
                float xx = ((tb >> c2) & 1u) ? p : 1.0f - p;
                float lg = fmaxf(__logf(xx), -100.0f);
                acc = fmaf(((eb >> c2) & 1u) ? 5.0f : 1.0f, -lg, acc);
            }
        }
    }

    for (int off = 32; off > 0; off >>= 1)
        acc += __shfl_down(acc, off);
    int wid = tid >> 6, lane = tid & 63;
    if (lane == 0) wsum[wid] = acc;
    __syncthreads();
    if (tid == 0) {
        float s = 0.0f;
#pragma unroll
        for (int i = 0; i < NT / 64; ++i) s += wsum[i];
        int bi = blockIdx.y * NBANDS + blockIdx.x;
        partials[bi] = s;
        __threadfence();
        u32 r = atomicAdd(done_ctr, 1u);
        lastf = (r == (u32)(nblocks - 1)) ? 1u : 0u;
    }
    __syncthreads();

    // ---- last block: final reduction (deterministic order) ----
    if (lastf) {
        __threadfence();
        double d = 0.0;
        for (int i = tid; i < nblocks; i += NT)
            d += (double)((volatile float*)partials)[i];
        for (int off = 32; off > 0; off >>= 1)
            d += __shfl_down(d, off);
        if (lane == 0) dsum[wid] = d;
        __syncthreads();
        if (tid == 0) {
            double s = 0.0;
#pragma unroll
            for (int i = 0; i < NT / 64; ++i) s += dsum[i];
            out[0] = (float)(s * invN);
            *done_ctr = 0;                    // self-reset for next launch
        }
    }
}

extern "C" void kernel_launch(void* const* d_in, const int* in_sizes, int n_in,
                              void* d_out, int out_size, void* d_ws, size_t ws_size,
                              hipStream_t stream)
{
    (void)n_in; (void)out_size; (void)ws_size;
    const float* pred   = (const float*)d_in[0];
    const float* target = (const float*)d_in[1];
    const int N = in_sizes[0];
    const int B = N / (H_IMG * W_IMG);

    // ws layout: [0,8KB) per-block partials; [8KB] done counter
    float* partials = (float*)d_ws;
    u32* done_ctr = (u32*)((char*)d_ws + 8192);
    hipMemsetAsync(done_ctr, 0, 4, stream);

    dim3 grid(NBANDS, B);
    edge_loss_kernel<<<grid, NT, 0, stream>>>(pred, target, partials, done_ctr,
                                              (float*)d_out, NBANDS * B,
                                              1.0 / (double)N);
}